// Round 4
// baseline (657.206 us; speedup 1.0000x reference)
//
#include <hip/hip_runtime.h>
#include <hip/hip_bf16.h>
#include <math.h>

typedef __attribute__((ext_vector_type(8))) __bf16 bf16x8;
typedef __attribute__((ext_vector_type(4))) __bf16 bf16x4;
typedef __attribute__((ext_vector_type(4))) float f32x4;

// LDS layout: F tile ALIASES A tile (A read in phase1 only; F built phase2/3,
// read phase4). F cols 43..63 hold stale-but-finite gather data; the matching
// rows of the packed wc1 B-fragments are ZERO, so they contribute nothing.
//  A/F tile: [64 rows][144 B]   A: 0-63 hi, 64-127 lo ; F: 0-127 (64 bf16)
//  H tile  : [64 rows][272 B]   h (L1 out), reused for h2 (L3 out)
#define LDS_A_OFF 0
#define LDS_H_OFF 9216
#define LDS_TOTAL 26624        // 6 blocks/CU

// workspace layout (bytes)
#define NBUCKET 4096
#define WS_WP   0              // packed weights, 32 KB
#define WS_HIST 32768          // 4096 u32
#define WS_CURS 49152          // 4096 u32
#define WS_PERM 65536          // N i32   (8 MB)
#define WS_SC   8454144        // sorted coords (24 MB)
#define WS_SR   33619968       // sorted ray_d  (24 MB)
#define WS_NEED 58785792UL

// ---------------------------------------------------------------------------
// Pack MLP weights into MFMA B-fragment layout (see round-2 comment).
//   frags 0-7: wd1 | 8-11: wd2 | 12-27: wc1 (rows 43-63 ZERO) | 28-31: wc2
// ---------------------------------------------------------------------------
__global__ void pack_weights(const float* __restrict__ wd1,
                             const float* __restrict__ wd2,
                             const float* __restrict__ wc1,
                             const float* __restrict__ wc2,
                             __bf16* __restrict__ wp)
{
    int t0 = threadIdx.x;
    for (int it = 0; it < 8; ++it) {
        int t = it * 256 + t0;
        int frag = t >> 6;
        int lane = t & 63;
        int kg = lane >> 4;
        int c  = lane & 15;
        for (int j = 0; j < 8; ++j) {
            int k = kg * 8 + j;
            float v;
            if (frag < 8) {
                v = wd1[k * 128 + frag * 16 + c];
            } else if (frag < 12) {
                v = wd2[((frag - 8) * 32 + k) * 16 + c];
            } else if (frag < 28) {
                int f = frag - 12;
                int kk = (f & 1) * 32 + k;
                v = (kk < 43) ? wc1[kk * 128 + (f >> 1) * 16 + c] : 0.0f;
            } else {
                int kk = (frag - 28) * 32 + k;
                v = (c < 3) ? wc2[kk * 3 + c] : 0.0f;
            }
            wp[frag * 512 + lane * 8 + j] = (__bf16)v;
        }
    }
}

// ---------------------------------------------------------------------------
// Counting sort of points into 4096 spatial buckets (16x16x16 of 8^3 cells).
// ---------------------------------------------------------------------------
__device__ __forceinline__ int bucket_key(float x, float y, float z) {
    int ix = (int)(x * 127.0f); ix = ix < 0 ? 0 : (ix > 127 ? 127 : ix);
    int iy = (int)(y * 127.0f); iy = iy < 0 ? 0 : (iy > 127 ? 127 : iy);
    int iz = (int)(z * 127.0f); iz = iz < 0 ? 0 : (iz > 127 ? 127 : iz);
    return ((ix >> 3) << 8) | ((iy >> 3) << 4) | (iz >> 3);
}

__global__ void zero_hist(unsigned int* __restrict__ h) {
    int i = blockIdx.x * blockDim.x + threadIdx.x;
    if (i < NBUCKET) h[i] = 0u;
}

__global__ __launch_bounds__(256) void hist_kernel(const float* __restrict__ coords,
                                                   unsigned int* __restrict__ hist,
                                                   int N)
{
    int i = blockIdx.x * blockDim.x + threadIdx.x;
    int stride = gridDim.x * blockDim.x;
    for (; i < N; i += stride) {
        size_t b = 3 * (size_t)i;
        atomicAdd(&hist[bucket_key(coords[b], coords[b + 1], coords[b + 2])], 1u);
    }
}

__global__ __launch_bounds__(256) void scan_kernel(const unsigned int* __restrict__ hist,
                                                   unsigned int* __restrict__ curs)
{
    int t = threadIdx.x;                 // 256 threads x 16 bins
    unsigned int pre[16];
    unsigned int run = 0;
#pragma unroll
    for (int j = 0; j < 16; ++j) { pre[j] = run; run += hist[t * 16 + j]; }
    unsigned lane = t & 63;
    int wid = t >> 6;
    unsigned inc = run;
    for (int d = 1; d < 64; d <<= 1) {
        unsigned u = __shfl_up(inc, d);
        if (lane >= (unsigned)d) inc += u;
    }
    __shared__ unsigned wt[4];
    if (lane == 63) wt[wid] = inc;
    __syncthreads();
    unsigned wbase = 0;
    for (int w = 0; w < wid; ++w) wbase += wt[w];
    unsigned excl = wbase + inc - run;   // exclusive prefix of this chunk
#pragma unroll
    for (int j = 0; j < 16; ++j) curs[t * 16 + j] = excl + pre[j];
}

__global__ __launch_bounds__(256) void scatter_kernel(const float* __restrict__ coords,
                                                      const float* __restrict__ rayd,
                                                      unsigned int* __restrict__ curs,
                                                      float* __restrict__ sc,
                                                      float* __restrict__ sr,
                                                      int* __restrict__ perm,
                                                      int N)
{
    int i = blockIdx.x * blockDim.x + threadIdx.x;
    int stride = gridDim.x * blockDim.x;
    for (; i < N; i += stride) {
        size_t b = 3 * (size_t)i;
        float x = coords[b], y = coords[b + 1], z = coords[b + 2];
        int key = bucket_key(x, y, z);
        unsigned dst = atomicAdd(&curs[key], 1u);
        size_t d3 = 3 * (size_t)dst;
        sc[d3] = x; sc[d3 + 1] = y; sc[d3 + 2] = z;
        sr[d3] = rayd[b]; sr[d3 + 1] = rayd[b + 1]; sr[d3 + 2] = rayd[b + 2];
        perm[dst] = i;
    }
}

// ---------------------------------------------------------------------------
// Fused NeRF forward: gather + 4 MFMA layers over (optionally sorted) points.
// ---------------------------------------------------------------------------
template <bool SORTED>
__global__ __launch_bounds__(256) void nerf_mfma(
    const float* __restrict__ coords,   // sorted if SORTED
    const float* __restrict__ ray_d,    // sorted if SORTED
    const float* __restrict__ grid,     // [128][128][128][32] f32
    const float* __restrict__ bd1,
    const float* __restrict__ bd2,
    const float* __restrict__ bc1,
    const float* __restrict__ bc2,
    const __bf16* __restrict__ wp,
    const int* __restrict__ perm,       // sorted slot -> original point
    float* __restrict__ out,            // [N][4]
    int ntiles)
{
    __shared__ __align__(16) char lds[LDS_TOTAL];
    const int tid  = threadIdx.x;
    const int lane = tid & 63;
    const int wid  = tid >> 6;
    const int c    = lane & 15;
    const int kg   = lane >> 4;

    // ---- hoist weight fragments & biases into registers -------------------
    const bf16x8* wpv = (const bf16x8*)wp;
    const int n0 = wid * 2, n1 = wid * 2 + 1;
    bf16x8 B1a = wpv[n0 * 64 + lane];
    bf16x8 B1b = wpv[n1 * 64 + lane];
    bf16x8 B2[4], B4[4], B3a[2], B3b[2];
#pragma unroll
    for (int kt = 0; kt < 4; ++kt) B2[kt] = wpv[(8 + kt) * 64 + lane];
#pragma unroll
    for (int kt = 0; kt < 2; ++kt) {
        B3a[kt] = wpv[(12 + n0 * 2 + kt) * 64 + lane];
        B3b[kt] = wpv[(12 + n1 * 2 + kt) * 64 + lane];
    }
#pragma unroll
    for (int kt = 0; kt < 4; ++kt) B4[kt] = wpv[(28 + kt) * 64 + lane];

    const float bias1a = bd1[n0 * 16 + c];
    const float bias1b = bd1[n1 * 16 + c];
    const float bias2  = bd2[c];
    const float bias3a = bc1[n0 * 16 + c];
    const float bias3b = bc1[n1 * 16 + c];
    const float bias4  = (c < 3) ? bc2[c] : 0.0f;

    const int wpt = wid * 16;

    // chunked XCD swizzle: physical XCD (blockIdx%8) gets a contiguous range
    const int per = (ntiles + gridDim.x - 1) / gridDim.x;
    int sb = blockIdx.x;
    if ((gridDim.x & 7) == 0)
        sb = (blockIdx.x & 7) * (gridDim.x >> 3) + (blockIdx.x >> 3);

    for (int j = 0; j < per; ++j) {
        const int tile = sb * per + j;
        if (tile >= ntiles) break;
        const int pbase = tile * 64;

        // ================= phase 0: loads + trilinear gather ===============
        float rv = (lane < 48) ? ray_d[(size_t)(pbase + wpt) * 3 + lane] : 0.0f;
        int pv = 0;
        if constexpr (SORTED) pv = perm[pbase + wpt + (lane & 15)];
        {
            float cval = (lane < 48) ? coords[(size_t)(pbase + wpt) * 3 + lane] : 0.0f;
            const int sub = lane & 7;
#pragma unroll
            for (int r = 0; r < 2; ++r) {
                int q = r * 8 + (lane >> 3);
                float cx = __shfl(cval, 3 * q + 0) * 127.0f;
                float cy = __shfl(cval, 3 * q + 1) * 127.0f;
                float cz = __shfl(cval, 3 * q + 2) * 127.0f;
                int ix = (int)floorf(cx); ix = ix < 0 ? 0 : (ix > 126 ? 126 : ix);
                int iy = (int)floorf(cy); iy = iy < 0 ? 0 : (iy > 126 ? 126 : iy);
                int iz = (int)floorf(cz); iz = iz < 0 ? 0 : (iz > 126 ? 126 : iz);
                float tx = cx - (float)ix;
                float ty = cy - (float)iy;
                float tz = cz - (float)iz;

                f32x4 facc = {0.0f, 0.0f, 0.0f, 0.0f};
#pragma unroll
                for (int cc = 0; cc < 8; ++cc) {
                    int ddx = (cc >> 2) & 1, ddy = (cc >> 1) & 1, ddz = cc & 1;
                    float w = (ddx ? tx : 1.0f - tx) *
                              (ddy ? ty : 1.0f - ty) *
                              (ddz ? tz : 1.0f - tz);
                    int idx = ((ix + ddx) << 14) + ((iy + ddy) << 7) + (iz + ddz);
                    f32x4 v = *((const f32x4*)(grid + (size_t)idx * 32) + sub);
                    facc[0] = fmaf(w, v[0], facc[0]);
                    facc[1] = fmaf(w, v[1], facc[1]);
                    facc[2] = fmaf(w, v[2], facc[2]);
                    facc[3] = fmaf(w, v[3], facc[3]);
                }
                bf16x4 hi, lo;
#pragma unroll
                for (int e = 0; e < 4; ++e) {
                    __bf16 h = (__bf16)facc[e];
                    hi[e] = h;
                    lo[e] = (__bf16)(facc[e] - (float)h);
                }
                char* arow = lds + LDS_A_OFF + (wpt + q) * 144;
                *(bf16x4*)(arow + sub * 8)      = hi;
                *(bf16x4*)(arow + 64 + sub * 8) = lo;
            }
        }
        __syncthreads();   // B0: A ready

        // ================= phase 1: L1 (32 -> 128, relu) ===================
        {
            f32x4 h[4][2];
#pragma unroll
            for (int m = 0; m < 4; ++m) {
                h[m][0] = (f32x4){bias1a, bias1a, bias1a, bias1a};
                h[m][1] = (f32x4){bias1b, bias1b, bias1b, bias1b};
            }
#pragma unroll
            for (int m = 0; m < 4; ++m) {
                const char* ab = lds + LDS_A_OFF + (m * 16 + c) * 144 + kg * 16;
                bf16x8 Ahi = *(const bf16x8*)(ab);
                bf16x8 Alo = *(const bf16x8*)(ab + 64);
                h[m][0] = __builtin_amdgcn_mfma_f32_16x16x32_bf16(Alo, B1a, h[m][0], 0, 0, 0);
                h[m][0] = __builtin_amdgcn_mfma_f32_16x16x32_bf16(Ahi, B1a, h[m][0], 0, 0, 0);
                h[m][1] = __builtin_amdgcn_mfma_f32_16x16x32_bf16(Alo, B1b, h[m][1], 0, 0, 0);
                h[m][1] = __builtin_amdgcn_mfma_f32_16x16x32_bf16(Ahi, B1b, h[m][1], 0, 0, 0);
            }
#pragma unroll
            for (int m = 0; m < 4; ++m) {
#pragma unroll
                for (int nn = 0; nn < 2; ++nn) {
                    int col = (nn ? n1 : n0) * 16 + c;
#pragma unroll
                    for (int i = 0; i < 4; ++i) {
                        int row = m * 16 + kg * 4 + i;
                        float v = fmaxf(h[m][nn][i], 0.0f);
                        *(__bf16*)(lds + LDS_H_OFF + row * 272 + col * 2) = (__bf16)v;
                    }
                }
            }
        }
        __syncthreads();   // B1: H ready (A fully consumed -> F may overwrite)

        // ================= phase 2: L2 (128 -> 16), density, dfeat->F ======
        {
            f32x4 d2 = {bias2, bias2, bias2, bias2};
#pragma unroll
            for (int kt = 0; kt < 4; ++kt) {
                bf16x8 A = *(const bf16x8*)(lds + LDS_H_OFF + (wpt + c) * 272 + kt * 64 + kg * 16);
                d2 = __builtin_amdgcn_mfma_f32_16x16x32_bf16(A, B2[kt], d2, 0, 0, 0);
            }
#pragma unroll
            for (int i = 0; i < 4; ++i) {
                int row = wpt + kg * 4 + i;
                *(__bf16*)(lds + LDS_A_OFF + row * 144 + c * 2) = (__bf16)d2[i];
                int tgt;
                if constexpr (SORTED) tgt = __shfl(pv, kg * 4 + i);
                else                  tgt = pbase + row;
                if (c == 0)
                    out[(size_t)tgt * 4 + 3] = fmaxf(d2[i], 0.0f);
            }
        }

        // ================= phase 3: view embedding -> F ====================
        {
            float ddx = __shfl(rv, 3 * c + 0);
            float ddy = __shfl(rv, 3 * c + 1);
            float ddz = __shfl(rv, 3 * c + 2);
            char* Frow = lds + LDS_A_OFF + (wpt + c) * 144;
            if (kg == 0) {
                *(__bf16*)(Frow + 16 * 2) = (__bf16)ddx;
                *(__bf16*)(Frow + 17 * 2) = (__bf16)ddy;
                *(__bf16*)(Frow + 18 * 2) = (__bf16)ddz;
            }
            float fr = (float)(1 << kg);
            float ax = ddx * fr, ay = ddy * fr, az = ddz * fr;
            *(__bf16*)(Frow + (19 + 3 * kg) * 2)     = (__bf16)__sinf(ax);
            *(__bf16*)(Frow + (19 + 3 * kg) * 2 + 2) = (__bf16)__sinf(ay);
            *(__bf16*)(Frow + (19 + 3 * kg) * 2 + 4) = (__bf16)__sinf(az);
            *(__bf16*)(Frow + (31 + 3 * kg) * 2)     = (__bf16)__cosf(ax);
            *(__bf16*)(Frow + (31 + 3 * kg) * 2 + 2) = (__bf16)__cosf(ay);
            *(__bf16*)(Frow + (31 + 3 * kg) * 2 + 4) = (__bf16)__cosf(az);
        }
        __syncthreads();   // B2: F ready

        // ================= phase 4: L3 (64 -> 128, relu) ===================
        {
            f32x4 h2[4][2];
#pragma unroll
            for (int m = 0; m < 4; ++m) {
                h2[m][0] = (f32x4){bias3a, bias3a, bias3a, bias3a};
                h2[m][1] = (f32x4){bias3b, bias3b, bias3b, bias3b};
            }
#pragma unroll
            for (int m = 0; m < 4; ++m) {
#pragma unroll
                for (int kt = 0; kt < 2; ++kt) {
                    bf16x8 A = *(const bf16x8*)(lds + LDS_A_OFF + (m * 16 + c) * 144 + kt * 64 + kg * 16);
                    h2[m][0] = __builtin_amdgcn_mfma_f32_16x16x32_bf16(A, B3a[kt], h2[m][0], 0, 0, 0);
                    h2[m][1] = __builtin_amdgcn_mfma_f32_16x16x32_bf16(A, B3b[kt], h2[m][1], 0, 0, 0);
                }
            }
#pragma unroll
            for (int m = 0; m < 4; ++m) {
#pragma unroll
                for (int nn = 0; nn < 2; ++nn) {
                    int col = (nn ? n1 : n0) * 16 + c;
#pragma unroll
                    for (int i = 0; i < 4; ++i) {
                        int row = m * 16 + kg * 4 + i;
                        float v = fmaxf(h2[m][nn][i], 0.0f);
                        *(__bf16*)(lds + LDS_H_OFF + row * 272 + col * 2) = (__bf16)v;
                    }
                }
            }
        }
        __syncthreads();   // B3: h2 ready (F consumed -> next gather may write)

        // ================= phase 5: L4 (128 -> 3), sigmoid, store ==========
        {
            f32x4 o4 = {bias4, bias4, bias4, bias4};
#pragma unroll
            for (int kt = 0; kt < 4; ++kt) {
                bf16x8 A = *(const bf16x8*)(lds + LDS_H_OFF + (wpt + c) * 272 + kt * 64 + kg * 16);
                o4 = __builtin_amdgcn_mfma_f32_16x16x32_bf16(A, B4[kt], o4, 0, 0, 0);
            }
#pragma unroll
            for (int i = 0; i < 4; ++i) {
                int tgt;
                if constexpr (SORTED) tgt = __shfl(pv, kg * 4 + i);
                else                  tgt = pbase + wpt + kg * 4 + i;
                float s = 1.0f / (1.0f + __expf(-o4[i]));
                if (c < 3)
                    out[(size_t)tgt * 4 + c] = s;
            }
        }
        // no trailing barrier needed: next phase-0 writes A/F (reads done at
        // B3) and H is only written after the next B0.
    }
}

extern "C" void kernel_launch(void* const* d_in, const int* in_sizes, int n_in,
                              void* d_out, int out_size, void* d_ws, size_t ws_size,
                              hipStream_t stream) {
    const float* coords = (const float*)d_in[0];
    const float* ray_d  = (const float*)d_in[1];
    const float* grid   = (const float*)d_in[2];
    const float* wd1    = (const float*)d_in[3];
    const float* bd1    = (const float*)d_in[4];
    const float* wd2    = (const float*)d_in[5];
    const float* bd2    = (const float*)d_in[6];
    const float* wc1    = (const float*)d_in[7];
    const float* bc1    = (const float*)d_in[8];
    const float* wc2    = (const float*)d_in[9];
    const float* bc2    = (const float*)d_in[10];
    float* out = (float*)d_out;

    int N = in_sizes[0] / 3;
    int ntiles = N >> 6;

    char* ws = (char*)d_ws;
    __bf16* wp = (__bf16*)(ws + WS_WP);

    pack_weights<<<1, 256, 0, stream>>>(wd1, wd2, wc1, wc2, wp);

    if (ws_size >= WS_NEED && (N & 63) == 0) {
        unsigned int* hist = (unsigned int*)(ws + WS_HIST);
        unsigned int* curs = (unsigned int*)(ws + WS_CURS);
        int*   perm = (int*)(ws + WS_PERM);
        float* sc   = (float*)(ws + WS_SC);
        float* sr   = (float*)(ws + WS_SR);

        zero_hist<<<16, 256, 0, stream>>>(hist);
        hist_kernel<<<2048, 256, 0, stream>>>(coords, hist, N);
        scan_kernel<<<1, 256, 0, stream>>>(hist, curs);
        scatter_kernel<<<2048, 256, 0, stream>>>(coords, ray_d, curs,
                                                 sc, sr, perm, N);
        nerf_mfma<true><<<8192, 256, 0, stream>>>(sc, sr, grid,
                                                  bd1, bd2, bc1, bc2,
                                                  wp, perm, out, ntiles);
    } else {
        nerf_mfma<false><<<8192, 256, 0, stream>>>(coords, ray_d, grid,
                                                   bd1, bd2, bc1, bc2,
                                                   wp, nullptr, out, ntiles);
    }
}

// Round 5
// 552.773 us; speedup vs baseline: 1.1889x; 1.1889x over previous
//
#include <hip/hip_runtime.h>
#include <hip/hip_bf16.h>
#include <math.h>

typedef __attribute__((ext_vector_type(8))) __bf16 bf16x8;
typedef __attribute__((ext_vector_type(4))) __bf16 bf16x4;
typedef __attribute__((ext_vector_type(4))) float f32x4;

// LDS layout (no aliasing): A read phase1; F built phase0(embed)+phase2(dfeat),
// read phase4; H written L1/L3, read L2/L4.
//  A: [64][144 B]  cols 0-31 hi, 32-63 lo (bf16)
//  H: [64][272 B]
//  F: [64][144 B]  cols 0-15 dfeat, 16-18 d, 19-30 sin, 31-42 cos, 43-63 zero
#define LDS_A_OFF 0
#define LDS_H_OFF 9216
#define LDS_F_OFF 26624
#define LDS_TOTAL 35840        // 4 blocks/CU

// ---- sort configuration ---------------------------------------------------
#define NBUCKET 4096           // 16x16x16 regions of 8^3 cells
#define HB      256            // histogram blocks
// workspace layout (bytes)
#define WS_WP   0UL                    // packed weights      32 KB
#define WS_MAT  32768UL                // [HB][NBUCKET] u32    4 MB
#define WS_TOT  4227072UL              // coltotal[NBUCKET]   16 KB
#define WS_BB   4243456UL              // bucketbase[NBUCKET] 16 KB
#define WS_PERM 4259840UL              // perm[N] i32          8 MB
#define WS_SC   12648448UL             // sorted coords       24 MB
#define WS_SR   37814272UL             // sorted ray_d        24 MB
#define WS_NEED 62980096UL

// ---------------------------------------------------------------------------
// Pack MLP weights into MFMA B-fragment layout.
//   frags 0-7: wd1 | 8-11: wd2 | 12-27: wc1 (rows 43-63 ZERO) | 28-31: wc2
// Frag f: 1024 B, lane l holds B[k=(l>>4)*8+j][n=l&15] of a 32x16 sub-tile.
// ---------------------------------------------------------------------------
__global__ void pack_weights(const float* __restrict__ wd1,
                             const float* __restrict__ wd2,
                             const float* __restrict__ wc1,
                             const float* __restrict__ wc2,
                             __bf16* __restrict__ wp)
{
    int t0 = threadIdx.x;
    for (int it = 0; it < 8; ++it) {
        int t = it * 256 + t0;
        int frag = t >> 6;
        int lane = t & 63;
        int kg = lane >> 4;
        int c  = lane & 15;
        for (int j = 0; j < 8; ++j) {
            int k = kg * 8 + j;
            float v;
            if (frag < 8) {
                v = wd1[k * 128 + frag * 16 + c];
            } else if (frag < 12) {
                v = wd2[((frag - 8) * 32 + k) * 16 + c];
            } else if (frag < 28) {
                int f = frag - 12;
                int kk = (f & 1) * 32 + k;
                v = (kk < 43) ? wc1[kk * 128 + (f >> 1) * 16 + c] : 0.0f;
            } else {
                int kk = (frag - 28) * 32 + k;
                v = (c < 3) ? wc2[kk * 3 + c] : 0.0f;
            }
            wp[frag * 512 + lane * 8 + j] = (__bf16)v;
        }
    }
}

__device__ __forceinline__ int bucket_key(float x, float y, float z) {
    int ix = (int)(x * 127.0f); ix = ix < 0 ? 0 : (ix > 127 ? 127 : ix);
    int iy = (int)(y * 127.0f); iy = iy < 0 ? 0 : (iy > 127 ? 127 : iy);
    int iz = (int)(z * 127.0f); iz = iz < 0 ? 0 : (iz > 127 ? 127 : iz);
    return ((ix >> 3) << 8) | ((iy >> 3) << 4) | (iz >> 3);
}

// ---------------------------------------------------------------------------
// Sort pass 1: per-block LDS histogram -> mat[block][NBUCKET]. No gl. atomics.
// ---------------------------------------------------------------------------
__global__ __launch_bounds__(256) void hist_lds(const float* __restrict__ coords,
                                                unsigned int* __restrict__ mat,
                                                int ppb)
{
    __shared__ unsigned int lh[NBUCKET];
    for (int i = threadIdx.x; i < NBUCKET; i += 256) lh[i] = 0u;
    __syncthreads();
    int base = blockIdx.x * ppb;
    for (int k = threadIdx.x; k < ppb; k += 256) {
        size_t b = 3 * (size_t)(base + k);
        atomicAdd(&lh[bucket_key(coords[b], coords[b + 1], coords[b + 2])], 1u);
    }
    __syncthreads();
    unsigned int* row = mat + (size_t)blockIdx.x * NBUCKET;
    for (int i = threadIdx.x; i < NBUCKET; i += 256) row[i] = lh[i];
}

// ---------------------------------------------------------------------------
// Sort pass 2: per-bucket exclusive scan over the HB blocks (in place) and
// column totals. One wave per bucket; lane l owns blocks 4l..4l+3.
// ---------------------------------------------------------------------------
__global__ __launch_bounds__(256) void col_scan(unsigned int* __restrict__ mat,
                                                unsigned int* __restrict__ total)
{
    int wid  = threadIdx.x >> 6;
    int lane = threadIdx.x & 63;
    int bkt  = blockIdx.x * 4 + wid;

    unsigned int v[4];
#pragma unroll
    for (int j = 0; j < 4; ++j)
        v[j] = mat[(size_t)(lane * 4 + j) * NBUCKET + bkt];
    unsigned int pre[4];
    unsigned int sum = 0;
#pragma unroll
    for (int j = 0; j < 4; ++j) { pre[j] = sum; sum += v[j]; }
    unsigned int inc = sum;
    for (int d = 1; d < 64; d <<= 1) {
        unsigned int u = __shfl_up(inc, d);
        if (lane >= d) inc += u;
    }
    unsigned int excl = inc - sum;
#pragma unroll
    for (int j = 0; j < 4; ++j)
        mat[(size_t)(lane * 4 + j) * NBUCKET + bkt] = excl + pre[j];
    if (lane == 63) total[bkt] = inc;
}

// ---------------------------------------------------------------------------
// Sort pass 3: exclusive scan of the 4096 bucket totals (single block).
// ---------------------------------------------------------------------------
__global__ __launch_bounds__(256) void bucket_scan(const unsigned int* __restrict__ total,
                                                   unsigned int* __restrict__ bbase)
{
    int t = threadIdx.x;
    unsigned int pre[16];
    unsigned int run = 0;
#pragma unroll
    for (int j = 0; j < 16; ++j) { pre[j] = run; run += total[t * 16 + j]; }
    unsigned int lane = t & 63;
    int wid = t >> 6;
    unsigned int inc = run;
    for (int d = 1; d < 64; d <<= 1) {
        unsigned int u = __shfl_up(inc, d);
        if (lane >= (unsigned)d) inc += u;
    }
    __shared__ unsigned int wt[4];
    if (lane == 63) wt[wid] = inc;
    __syncthreads();
    unsigned int wbase = 0;
    for (int w = 0; w < wid; ++w) wbase += wt[w];
    unsigned int excl = wbase + inc - run;
#pragma unroll
    for (int j = 0; j < 16; ++j) bbase[t * 16 + j] = excl + pre[j];
}

// ---------------------------------------------------------------------------
// Sort pass 4: scatter with LDS cursors (cur = bucketbase + block base).
// ---------------------------------------------------------------------------
__global__ __launch_bounds__(256) void scatter_lds(const float* __restrict__ coords,
                                                   const float* __restrict__ rayd,
                                                   const unsigned int* __restrict__ mat,
                                                   const unsigned int* __restrict__ bbase,
                                                   float* __restrict__ sc,
                                                   float* __restrict__ sr,
                                                   int* __restrict__ perm,
                                                   int ppb)
{
    __shared__ unsigned int cur[NBUCKET];
    const unsigned int* row = mat + (size_t)blockIdx.x * NBUCKET;
    for (int i = threadIdx.x; i < NBUCKET; i += 256)
        cur[i] = bbase[i] + row[i];
    __syncthreads();
    int base = blockIdx.x * ppb;
    for (int k = threadIdx.x; k < ppb; k += 256) {
        int i = base + k;
        size_t b = 3 * (size_t)i;
        float x = coords[b], y = coords[b + 1], z = coords[b + 2];
        unsigned int dst = atomicAdd(&cur[bucket_key(x, y, z)], 1u);
        size_t d3 = 3 * (size_t)dst;
        sc[d3] = x; sc[d3 + 1] = y; sc[d3 + 2] = z;
        sr[d3] = rayd[b]; sr[d3 + 1] = rayd[b + 1]; sr[d3 + 2] = rayd[b + 2];
        perm[dst] = i;
    }
}

// ---------------------------------------------------------------------------
// Fused NeRF forward: gather + 4 MFMA layers over (optionally sorted) points.
// ---------------------------------------------------------------------------
template <bool SORTED>
__global__ __launch_bounds__(256) void nerf_mfma(
    const float* __restrict__ coords,
    const float* __restrict__ ray_d,
    const float* __restrict__ grid,     // [128][128][128][32] f32
    const float* __restrict__ bd1,
    const float* __restrict__ bd2,
    const float* __restrict__ bc1,
    const float* __restrict__ bc2,
    const __bf16* __restrict__ wp,
    const int* __restrict__ perm,
    float* __restrict__ out,            // [N][4]
    int ntiles)
{
    __shared__ __align__(16) char lds[LDS_TOTAL];
    const int tid  = threadIdx.x;
    const int lane = tid & 63;
    const int wid  = tid >> 6;
    const int c    = lane & 15;
    const int kg   = lane >> 4;

    // ---- hoist weight fragments & biases into registers -------------------
    const bf16x8* wpv = (const bf16x8*)wp;
    const int n0 = wid * 2, n1 = wid * 2 + 1;
    bf16x8 B1a = wpv[n0 * 64 + lane];
    bf16x8 B1b = wpv[n1 * 64 + lane];
    bf16x8 B2[4], B4[4], B3a[2], B3b[2];
#pragma unroll
    for (int kt = 0; kt < 4; ++kt) B2[kt] = wpv[(8 + kt) * 64 + lane];
#pragma unroll
    for (int kt = 0; kt < 2; ++kt) {
        B3a[kt] = wpv[(12 + n0 * 2 + kt) * 64 + lane];
        B3b[kt] = wpv[(12 + n1 * 2 + kt) * 64 + lane];
    }
#pragma unroll
    for (int kt = 0; kt < 4; ++kt) B4[kt] = wpv[(28 + kt) * 64 + lane];

    const float bias1a = bd1[n0 * 16 + c];
    const float bias1b = bd1[n1 * 16 + c];
    const float bias2  = bd2[c];
    const float bias3a = bc1[n0 * 16 + c];
    const float bias3b = bc1[n1 * 16 + c];
    const float bias4  = (c < 3) ? bc2[c] : 0.0f;

    // F pad cols 43..63: zero once (matching wc1 frag rows are zero, but the
    // stale LDS pattern could be Inf/NaN; 0*anything keeps it clean).
    for (int i = tid; i < 64 * 21; i += 256) {
        int row = i / 21, col = 43 + i % 21;
        *(__bf16*)(lds + LDS_F_OFF + row * 144 + col * 2) = (__bf16)0.0f;
    }

    const int wpt = wid * 16;

    // chunked XCD swizzle: physical XCD (blockIdx%8) gets a contiguous range
    const int per = (ntiles + gridDim.x - 1) / gridDim.x;
    int sb = blockIdx.x;
    if ((gridDim.x & 7) == 0)
        sb = (blockIdx.x & 7) * (gridDim.x >> 3) + (blockIdx.x >> 3);

    for (int j = 0; j < per; ++j) {
        const int tile = sb * per + j;
        if (tile >= ntiles) break;
        const int pbase = tile * 64;

        // ===== phase 0: gather -> A, view embedding -> F, perm load =======
        float rv = (lane < 48) ? ray_d[(size_t)(pbase + wpt) * 3 + lane] : 0.0f;
        int pv = 0;
        if constexpr (SORTED) pv = perm[pbase + wpt + (lane & 15)];
        {
            float cval = (lane < 48) ? coords[(size_t)(pbase + wpt) * 3 + lane] : 0.0f;
            const int sub = lane & 7;
#pragma unroll
            for (int r = 0; r < 2; ++r) {
                int q = r * 8 + (lane >> 3);
                float cx = __shfl(cval, 3 * q + 0) * 127.0f;
                float cy = __shfl(cval, 3 * q + 1) * 127.0f;
                float cz = __shfl(cval, 3 * q + 2) * 127.0f;
                int ix = (int)floorf(cx); ix = ix < 0 ? 0 : (ix > 126 ? 126 : ix);
                int iy = (int)floorf(cy); iy = iy < 0 ? 0 : (iy > 126 ? 126 : iy);
                int iz = (int)floorf(cz); iz = iz < 0 ? 0 : (iz > 126 ? 126 : iz);
                float tx = cx - (float)ix;
                float ty = cy - (float)iy;
                float tz = cz - (float)iz;

                f32x4 facc = {0.0f, 0.0f, 0.0f, 0.0f};
#pragma unroll
                for (int cc = 0; cc < 8; ++cc) {
                    int ddx = (cc >> 2) & 1, ddy = (cc >> 1) & 1, ddz = cc & 1;
                    float w = (ddx ? tx : 1.0f - tx) *
                              (ddy ? ty : 1.0f - ty) *
                              (ddz ? tz : 1.0f - tz);
                    int idx = ((ix + ddx) << 14) + ((iy + ddy) << 7) + (iz + ddz);
                    f32x4 v = *((const f32x4*)(grid + (size_t)idx * 32) + sub);
                    facc[0] = fmaf(w, v[0], facc[0]);
                    facc[1] = fmaf(w, v[1], facc[1]);
                    facc[2] = fmaf(w, v[2], facc[2]);
                    facc[3] = fmaf(w, v[3], facc[3]);
                }
                bf16x4 hi, lo;
#pragma unroll
                for (int e = 0; e < 4; ++e) {
                    __bf16 h = (__bf16)facc[e];
                    hi[e] = h;
                    lo[e] = (__bf16)(facc[e] - (float)h);
                }
                char* arow = lds + LDS_A_OFF + (wpt + q) * 144;
                *(bf16x4*)(arow + sub * 8)      = hi;
                *(bf16x4*)(arow + 64 + sub * 8) = lo;
            }
            // view embedding for this wave's 16 rows (overlaps gather latency)
            float ddx = __shfl(rv, 3 * c + 0);
            float ddy = __shfl(rv, 3 * c + 1);
            float ddz = __shfl(rv, 3 * c + 2);
            char* Frow = lds + LDS_F_OFF + (wpt + c) * 144;
            if (kg == 0) {
                *(__bf16*)(Frow + 16 * 2) = (__bf16)ddx;
                *(__bf16*)(Frow + 17 * 2) = (__bf16)ddy;
                *(__bf16*)(Frow + 18 * 2) = (__bf16)ddz;
            }
            float fr = (float)(1 << kg);
            float ax = ddx * fr, ay = ddy * fr, az = ddz * fr;
            *(__bf16*)(Frow + (19 + 3 * kg) * 2)     = (__bf16)__sinf(ax);
            *(__bf16*)(Frow + (19 + 3 * kg) * 2 + 2) = (__bf16)__sinf(ay);
            *(__bf16*)(Frow + (19 + 3 * kg) * 2 + 4) = (__bf16)__sinf(az);
            *(__bf16*)(Frow + (31 + 3 * kg) * 2)     = (__bf16)__cosf(ax);
            *(__bf16*)(Frow + (31 + 3 * kg) * 2 + 2) = (__bf16)__cosf(ay);
            *(__bf16*)(Frow + (31 + 3 * kg) * 2 + 4) = (__bf16)__cosf(az);
        }
        __syncthreads();   // B0: A + F-embed ready

        // ================= phase 1: L1 (32 -> 128, relu) ===================
        {
            f32x4 h[4][2];
#pragma unroll
            for (int m = 0; m < 4; ++m) {
                h[m][0] = (f32x4){bias1a, bias1a, bias1a, bias1a};
                h[m][1] = (f32x4){bias1b, bias1b, bias1b, bias1b};
            }
            __builtin_amdgcn_s_setprio(1);
#pragma unroll
            for (int m = 0; m < 4; ++m) {
                const char* ab = lds + LDS_A_OFF + (m * 16 + c) * 144 + kg * 16;
                bf16x8 Ahi = *(const bf16x8*)(ab);
                bf16x8 Alo = *(const bf16x8*)(ab + 64);
                h[m][0] = __builtin_amdgcn_mfma_f32_16x16x32_bf16(Alo, B1a, h[m][0], 0, 0, 0);
                h[m][0] = __builtin_amdgcn_mfma_f32_16x16x32_bf16(Ahi, B1a, h[m][0], 0, 0, 0);
                h[m][1] = __builtin_amdgcn_mfma_f32_16x16x32_bf16(Alo, B1b, h[m][1], 0, 0, 0);
                h[m][1] = __builtin_amdgcn_mfma_f32_16x16x32_bf16(Ahi, B1b, h[m][1], 0, 0, 0);
            }
            __builtin_amdgcn_s_setprio(0);
#pragma unroll
            for (int m = 0; m < 4; ++m) {
#pragma unroll
                for (int nn = 0; nn < 2; ++nn) {
                    int col = (nn ? n1 : n0) * 16 + c;
#pragma unroll
                    for (int i = 0; i < 4; ++i) {
                        int row = m * 16 + kg * 4 + i;
                        float v = fmaxf(h[m][nn][i], 0.0f);
                        *(__bf16*)(lds + LDS_H_OFF + row * 272 + col * 2) = (__bf16)v;
                    }
                }
            }
        }
        __syncthreads();   // B1: H ready

        // ================= phase 2: L2 (128 -> 16), density, dfeat->F ======
        {
            f32x4 d2 = {bias2, bias2, bias2, bias2};
#pragma unroll
            for (int kt = 0; kt < 4; ++kt) {
                bf16x8 A = *(const bf16x8*)(lds + LDS_H_OFF + (wpt + c) * 272 + kt * 64 + kg * 16);
                d2 = __builtin_amdgcn_mfma_f32_16x16x32_bf16(A, B2[kt], d2, 0, 0, 0);
            }
#pragma unroll
            for (int i = 0; i < 4; ++i) {
                int row = wpt + kg * 4 + i;
                *(__bf16*)(lds + LDS_F_OFF + row * 144 + c * 2) = (__bf16)d2[i];
                int tgt;
                if constexpr (SORTED) tgt = __shfl(pv, kg * 4 + i);
                else                  tgt = pbase + row;
                if (c == 0)
                    out[(size_t)tgt * 4 + 3] = fmaxf(d2[i], 0.0f);
            }
        }
        __syncthreads();   // B2: F complete

        // ================= phase 4: L3 (64 -> 128, relu) ===================
        {
            f32x4 h2[4][2];
#pragma unroll
            for (int m = 0; m < 4; ++m) {
                h2[m][0] = (f32x4){bias3a, bias3a, bias3a, bias3a};
                h2[m][1] = (f32x4){bias3b, bias3b, bias3b, bias3b};
            }
            __builtin_amdgcn_s_setprio(1);
#pragma unroll
            for (int m = 0; m < 4; ++m) {
#pragma unroll
                for (int kt = 0; kt < 2; ++kt) {
                    bf16x8 A = *(const bf16x8*)(lds + LDS_F_OFF + (m * 16 + c) * 144 + kt * 64 + kg * 16);
                    h2[m][0] = __builtin_amdgcn_mfma_f32_16x16x32_bf16(A, B3a[kt], h2[m][0], 0, 0, 0);
                    h2[m][1] = __builtin_amdgcn_mfma_f32_16x16x32_bf16(A, B3b[kt], h2[m][1], 0, 0, 0);
                }
            }
            __builtin_amdgcn_s_setprio(0);
#pragma unroll
            for (int m = 0; m < 4; ++m) {
#pragma unroll
                for (int nn = 0; nn < 2; ++nn) {
                    int col = (nn ? n1 : n0) * 16 + c;
#pragma unroll
                    for (int i = 0; i < 4; ++i) {
                        int row = m * 16 + kg * 4 + i;
                        float v = fmaxf(h2[m][nn][i], 0.0f);
                        *(__bf16*)(lds + LDS_H_OFF + row * 272 + col * 2) = (__bf16)v;
                    }
                }
            }
        }
        __syncthreads();   // B3: h2 ready

        // ================= phase 5: L4 (128 -> 3), sigmoid, store ==========
        {
            f32x4 o4 = {bias4, bias4, bias4, bias4};
#pragma unroll
            for (int kt = 0; kt < 4; ++kt) {
                bf16x8 A = *(const bf16x8*)(lds + LDS_H_OFF + (wpt + c) * 272 + kt * 64 + kg * 16);
                o4 = __builtin_amdgcn_mfma_f32_16x16x32_bf16(A, B4[kt], o4, 0, 0, 0);
            }
#pragma unroll
            for (int i = 0; i < 4; ++i) {
                int tgt;
                if constexpr (SORTED) tgt = __shfl(pv, kg * 4 + i);
                else                  tgt = pbase + wpt + kg * 4 + i;
                float s = 1.0f / (1.0f + __expf(-o4[i]));
                if (c < 3)
                    out[(size_t)tgt * 4 + c] = s;
            }
        }
        __syncthreads();   // B4: H reads done before next L1 writes; F-embed
                           // writes of next tile happen after this barrier.
    }
}

extern "C" void kernel_launch(void* const* d_in, const int* in_sizes, int n_in,
                              void* d_out, int out_size, void* d_ws, size_t ws_size,
                              hipStream_t stream) {
    const float* coords = (const float*)d_in[0];
    const float* ray_d  = (const float*)d_in[1];
    const float* grid   = (const float*)d_in[2];
    const float* wd1    = (const float*)d_in[3];
    const float* bd1    = (const float*)d_in[4];
    const float* wd2    = (const float*)d_in[5];
    const float* bd2    = (const float*)d_in[6];
    const float* wc1    = (const float*)d_in[7];
    const float* bc1    = (const float*)d_in[8];
    const float* wc2    = (const float*)d_in[9];
    const float* bc2    = (const float*)d_in[10];
    float* out = (float*)d_out;

    int N = in_sizes[0] / 3;
    int ntiles = N >> 6;

    char* ws = (char*)d_ws;
    __bf16* wp = (__bf16*)(ws + WS_WP);

    pack_weights<<<1, 256, 0, stream>>>(wd1, wd2, wc1, wc2, wp);

    if (ws_size >= WS_NEED && (N % (HB * 64)) == 0) {
        unsigned int* mat   = (unsigned int*)(ws + WS_MAT);
        unsigned int* total = (unsigned int*)(ws + WS_TOT);
        unsigned int* bbase = (unsigned int*)(ws + WS_BB);
        int*   perm = (int*)(ws + WS_PERM);
        float* sc   = (float*)(ws + WS_SC);
        float* sr   = (float*)(ws + WS_SR);
        int ppb = N / HB;

        hist_lds<<<HB, 256, 0, stream>>>(coords, mat, ppb);
        col_scan<<<NBUCKET / 4, 256, 0, stream>>>(mat, total);
        bucket_scan<<<1, 256, 0, stream>>>(total, bbase);
        scatter_lds<<<HB, 256, 0, stream>>>(coords, ray_d, mat, bbase,
                                            sc, sr, perm, ppb);
        nerf_mfma<true><<<8192, 256, 0, stream>>>(sc, sr, grid,
                                                  bd1, bd2, bc1, bc2,
                                                  wp, perm, out, ntiles);
    } else {
        nerf_mfma<false><<<8192, 256, 0, stream>>>(coords, ray_d, grid,
                                                   bd1, bd2, bc1, bc2,
                                                   wp, nullptr, out, ntiles);
    }
}